// Round 1
// baseline (1137.072 us; speedup 1.0000x reference)
//
#include <hip/hip_runtime.h>
#include <math.h>

// Problem constants (from reference setup_inputs)
#define BB   32
#define DD   128
#define HH   64
#define WW   64
#define KK   1024
#define HWW  (HH * WW)      // 4096 pixels per batch image
#define NPIX (BB * HWW)     // 131072 total pixels
#define KT   128            // codewords per LDS tile (64 KB tile)

// ---------------------------------------------------------------------------
// Prep: transpose weight [D][K] -> wT [K][D] (contiguous codeword rows) and
// compute e2[k] = sum_d w[d,k]^2 with numpy's rounding: sequential over d
// ascending, separate mul/add rounding (no FMA).
// ---------------------------------------------------------------------------
__global__ void prep_kernel(const float* __restrict__ w,
                            float* __restrict__ wT,
                            float* __restrict__ e2) {
    int k = blockIdx.x * blockDim.x + threadIdx.x;
    if (k >= KK) return;
    float acc = 0.0f;
    for (int d = 0; d < DD; ++d) {
        float v = w[d * KK + k];        // coalesced across k
        wT[k * DD + d] = v;
        acc = __fadd_rn(acc, __fmul_rn(v, v));   // numpy-order, no FMA
    }
    e2[k] = acc;
}

// ---------------------------------------------------------------------------
// Main: one thread = one pixel. x[0..127] held in VGPRs. Codebook streamed
// through LDS in 128-codeword tiles (all lanes read the same LDS address ->
// broadcast, conflict-free). Accumulation per codeword is STRICTLY sequential
// over d with separate rounded mul/add to bit-match the numpy reference
// (argmin has sub-ULP ties; FMA or reassociation flips winners).
// ---------------------------------------------------------------------------
__global__ __launch_bounds__(256) void vq_argmin_gather(
        const float* __restrict__ x,
        const float* __restrict__ wT,
        const float* __restrict__ e2,
        float* __restrict__ out) {
    __shared__ float lds_w[KT * DD];   // 64 KB -> 2 blocks/CU
    __shared__ float lds_e2[KT];

    const int tid = threadIdx.x;
    const int p   = blockIdx.x * 256 + tid;   // pixel id; blocks never straddle b
    const int b   = p >> 12;                  // / 4096
    const int hw  = p & (HWW - 1);

    // Load this pixel's x vector (coalesced across lanes for each d)
    const float* xp = x + (size_t)b * DD * HWW + hw;
    float xv[DD];
#pragma unroll
    for (int d = 0; d < DD; ++d) xv[d] = xp[(size_t)d * HWW];

    // x2: order-invariant for argmin (uniform exact-grid shift across k)
    float x2 = 0.0f;
#pragma unroll
    for (int d = 0; d < DD; ++d) x2 = __fadd_rn(x2, __fmul_rn(xv[d], xv[d]));

    float best  = INFINITY;
    int   bestk = 0;

    for (int kt = 0; kt < KK; kt += KT) {
        __syncthreads();
        {
            const float4* src = (const float4*)(wT + (size_t)kt * DD);
            float4*       dst = (float4*)lds_w;
            for (int i = tid; i < KT * DD / 4; i += 256) dst[i] = src[i];
            if (tid < KT) lds_e2[tid] = e2[kt + tid];
        }
        __syncthreads();

        // two codewords per iteration: two independent 4-cyc add chains
        for (int kk = 0; kk < KT; kk += 2) {
            const float4* w0 = (const float4*)(lds_w + (kk + 0) * DD);
            const float4* w1 = (const float4*)(lds_w + (kk + 1) * DD);
            float a0 = 0.0f, a1 = 0.0f;
#pragma unroll
            for (int d4 = 0; d4 < DD / 4; ++d4) {
                float4 wv0 = w0[d4];
                float4 wv1 = w1[d4];
                a0 = __fadd_rn(a0, __fmul_rn(xv[4*d4+0], wv0.x));
                a1 = __fadd_rn(a1, __fmul_rn(xv[4*d4+0], wv1.x));
                a0 = __fadd_rn(a0, __fmul_rn(xv[4*d4+1], wv0.y));
                a1 = __fadd_rn(a1, __fmul_rn(xv[4*d4+1], wv1.y));
                a0 = __fadd_rn(a0, __fmul_rn(xv[4*d4+2], wv0.z));
                a1 = __fadd_rn(a1, __fmul_rn(xv[4*d4+2], wv1.z));
                a0 = __fadd_rn(a0, __fmul_rn(xv[4*d4+3], wv0.w));
                a1 = __fadd_rn(a1, __fmul_rn(xv[4*d4+3], wv1.w));
            }
            // numpy op order: (x2 - 2*xe) + e2, each step rounded; 2*a exact
            float d20 = __fadd_rn(__fsub_rn(x2, 2.0f * a0), lds_e2[kk + 0]);
            float d21 = __fadd_rn(__fsub_rn(x2, 2.0f * a1), lds_e2[kk + 1]);
            // strict < keeps first occurrence (np.argmin tie rule); order kk,kk+1
            if (d20 < best) { best = d20; bestk = kt + kk; }
            if (d21 < best) { best = d21; bestk = kt + kk + 1; }
        }
    }

    // Output 1: argmin as float (d_out is one float32 buffer, outputs concat)
    out[(size_t)DD * NPIX + p] = (float)bestk;

    // Output 0: gather winning codeword, scatter to [b, d, h, w]
    const float4* wbest = (const float4*)(wT + (size_t)bestk * DD);
    float* op = out + (size_t)b * DD * HWW + hw;
#pragma unroll
    for (int d4 = 0; d4 < DD / 4; ++d4) {
        float4 wv = wbest[d4];               // L2-resident, divergent but tiny
        op[(size_t)(4*d4+0) * HWW] = wv.x;   // coalesced across lanes per d
        op[(size_t)(4*d4+1) * HWW] = wv.y;
        op[(size_t)(4*d4+2) * HWW] = wv.z;
        op[(size_t)(4*d4+3) * HWW] = wv.w;
    }
}

extern "C" void kernel_launch(void* const* d_in, const int* in_sizes, int n_in,
                              void* d_out, int out_size, void* d_ws, size_t ws_size,
                              hipStream_t stream) {
    const float* x = (const float*)d_in[0];   // [32,128,64,64]
    const float* w = (const float*)d_in[1];   // [128,1024]
    float* out = (float*)d_out;               // [32*128*64*64] result + [131072] argmin
    float* wT  = (float*)d_ws;                // K*D floats = 512 KB
    float* e2  = wT + (size_t)KK * DD;        // +1024 floats

    prep_kernel<<<dim3(KK / 256), dim3(256), 0, stream>>>(w, wT, e2);
    vq_argmin_gather<<<dim3(NPIX / 256), dim3(256), 0, stream>>>(x, wT, e2, out);
}